// Round 5
// baseline (124.652 us; speedup 1.0000x reference)
//
#include <hip/hip_runtime.h>
#include <math.h>

typedef unsigned long long u64;
typedef unsigned int u32;
typedef float f32x4 __attribute__((ext_vector_type(4)));

#define NB 256       // batch
#define NQ 1000      // queries
#define NC 80        // classes
#define QC 80000     // NQ*NC per row
#define NQ4 (QC / 4) // 20000 float4s per row
#define TOPK 300
#define CAP 512      // candidate capacity = bitonic size (power of 2)
#define NTHREADS 1024

// T=2.585: P(N(0,1) > 2.585) ~ 0.00487 -> ~390 +/- 20 candidates per row.
// 300 is -4.6 sigma, 512 is +6.2 sigma. Bisection fallback below guards
// out-of-window rows (correctness-preserving, never taken on this data).
#define T_INIT 2.585f

__device__ __forceinline__ u64 shfl_xor_u64(u64 v, int mask) {
  int lo = __shfl_xor((int)(u32)(v & 0xFFFFFFFFull), mask, 64);
  int hi = __shfl_xor((int)(u32)(v >> 32), mask, 64);
  return ((u64)(u32)hi << 32) | (u64)(u32)lo;
}

// key = (positive-float logit bits << 32) | (0xFFFFFFFF - flat_idx)
// Sigmoid is monotone => top-k on logits == top-k on scores; descending sort
// on this key reproduces jax.lax.top_k order (ties: lower index first).
__global__ __launch_bounds__(NTHREADS) void postproc_kernel(
    const float* __restrict__ logits,
    const float4* __restrict__ boxes,
    float* __restrict__ out) {
  const int row = blockIdx.x;
  const int tid = threadIdx.x;

  __shared__ u64 s_keys[CAP];
  __shared__ int s_cnt;

  const f32x4* lp = (const f32x4*)logits + (size_t)row * NQ4;

  float T = T_INIT;
  float tlo = -1.0f, thi = 7.0f;  // bisection bounds for fallback
  int cnt = 0;

  auto filt = [&](float x, u32 idx) {
    if (x > T) {
      int pos = atomicAdd(&s_cnt, 1);
      if (pos < CAP)
        s_keys[pos] = ((u64)__float_as_uint(x) << 32) | (u64)(0xFFFFFFFFu - idx);
    }
  };

  for (int attempt = 0; attempt < 24; ++attempt) {
    __syncthreads();  // protect s_cnt reset vs. prior-iteration readers
    if (tid == 0) s_cnt = 0;
    __syncthreads();

    // scan: 8x unrolled non-temporal streaming loads (single-use data --
    // bypass cache allocation; 32 loads in flight per thread window)
    for (int i = tid; i < 16384; i += 8 * NTHREADS) {
      f32x4 v[8];
#pragma unroll
      for (int u = 0; u < 8; ++u)
        v[u] = __builtin_nontemporal_load(lp + i + u * NTHREADS);
#pragma unroll
      for (int u = 0; u < 8; ++u) {
        int iu = i + u * NTHREADS;
        filt(v[u].x, 4 * iu);
        filt(v[u].y, 4 * iu + 1);
        filt(v[u].z, 4 * iu + 2);
        filt(v[u].w, 4 * iu + 3);
      }
    }
    // tail: 16384..19999 (3616 float4s), 4x unrolled with bounds checks
    {
      int i = 16384 + tid;
      f32x4 v[4];
      bool ok[4];
#pragma unroll
      for (int u = 0; u < 4; ++u) {
        int iu = i + u * NTHREADS;
        ok[u] = iu < NQ4;
        if (ok[u]) v[u] = __builtin_nontemporal_load(lp + iu);
      }
#pragma unroll
      for (int u = 0; u < 4; ++u) {
        if (ok[u]) {
          int iu = i + u * NTHREADS;
          filt(v[u].x, 4 * iu);
          filt(v[u].y, 4 * iu + 1);
          filt(v[u].z, 4 * iu + 2);
          filt(v[u].w, 4 * iu + 3);
        }
      }
    }

    __syncthreads();
    cnt = s_cnt;
    if (cnt >= TOPK && cnt <= CAP) break;
    // bisection: larger T -> fewer candidates
    if (cnt < TOPK) thi = T; else tlo = T;
    T = 0.5f * (tlo + thi);
  }
  if (cnt > CAP) cnt = CAP;

  // ---- register bitonic sort, descending, CAP=512 keys on threads 0..511.
  // Strides <=32: __shfl_xor (no barriers, 39 half-stages).
  // Strides 64/128/256: LDS exchange (6 half-stages, 12 barriers).
  u64 key = 0;
  if (tid < CAP && tid < cnt) key = s_keys[tid];

  for (int k = 2; k <= CAP; k <<= 1) {
    for (int j = k >> 1; j > 0; j >>= 1) {
      if (j >= 64) {
        __syncthreads();
        if (tid < CAP) s_keys[tid] = key;
        __syncthreads();
        if (tid < CAP) {
          u64 other = s_keys[tid ^ j];
          bool iLower = (tid & j) == 0;
          bool dirAsc = (tid & k) != 0;  // k=CAP => all-descending final
          bool keepMin = (dirAsc == iLower);
          key = keepMin ? (key < other ? key : other)
                        : (key > other ? key : other);
        }
      } else if (tid < CAP) {  // wave-uniform branch (tids >=512 whole waves)
        u64 other = shfl_xor_u64(key, j);
        bool iLower = (tid & j) == 0;
        bool dirAsc = (tid & k) != 0;
        bool keepMin = (dirAsc == iLower);
        key = keepMin ? (key < other ? key : other)
                      : (key > other ? key : other);
      }
    }
  }

  // ---- epilogue: thread tid holds the rank-tid key in register
  if (tid < TOPK) {
    float* labels_out = out;                  // [NB, TOPK]
    float* boxes_out = out + NB * TOPK;       // [NB, TOPK, 4]
    float* scores_out = out + NB * TOPK * 5;  // [NB, TOPK]

    float lab = 0.0f, score = 0.0f;
    float4 bo = make_float4(0.0f, 0.0f, 0.0f, 0.0f);
    if (tid < cnt) {
      u32 idx = 0xFFFFFFFFu - (u32)(key & 0xFFFFFFFFull);
      float x = __uint_as_float((u32)(key >> 32));
      int q = (int)(idx / NC);
      int c = (int)(idx - (u32)q * NC);
      lab = (float)c;
      score = (float)(1.0 / (1.0 + exp(-(double)x)));  // exact f32 sigmoid
      float4 bb = boxes[(size_t)row * NQ + q];
      float hw = 0.5f * bb.z, hh = 0.5f * bb.w;
      bo.x = bb.x - hw;
      bo.y = bb.y - hh;
      bo.z = bb.x + hw;
      bo.w = bb.y + hh;
    }
    labels_out[row * TOPK + tid] = lab;
    scores_out[row * TOPK + tid] = score;
    ((float4*)boxes_out)[row * TOPK + tid] = bo;
  }
}

extern "C" void kernel_launch(void* const* d_in, const int* in_sizes, int n_in,
                              void* d_out, int out_size, void* d_ws, size_t ws_size,
                              hipStream_t stream) {
  const float* logits = (const float*)d_in[0];
  const float4* boxes = (const float4*)d_in[1];
  float* out = (float*)d_out;
  postproc_kernel<<<NB, NTHREADS, 0, stream>>>(logits, boxes, out);
}

// Round 6
// 123.367 us; speedup vs baseline: 1.0104x; 1.0104x over previous
//
#include <hip/hip_runtime.h>
#include <math.h>

typedef unsigned long long u64;
typedef unsigned int u32;

#define NB 256       // batch
#define NQ 1000      // queries
#define NC 80        // classes
#define QC 80000     // NQ*NC per row
#define NQ4 (QC / 4) // 20000 float4s per row
#define TOPK 300
#define CAP 512      // candidate capacity = bitonic size (power of 2)
#define NTHREADS 1024

// T=2.585: P(N(0,1) > 2.585) ~ 0.00487 -> ~390 +/- 20 candidates per row.
// 300 is -4.6 sigma, 512 is +6.2 sigma. Bisection fallback below guards
// out-of-window rows (correctness-preserving, never taken on this data).
#define T_INIT 2.585f

__device__ __forceinline__ u64 shfl_xor_u64(u64 v, int mask) {
  int lo = __shfl_xor((int)(u32)(v & 0xFFFFFFFFull), mask, 64);
  int hi = __shfl_xor((int)(u32)(v >> 32), mask, 64);
  return ((u64)(u32)hi << 32) | (u64)(u32)lo;
}

// key = (positive-float logit bits << 32) | (0xFFFFFFFF - flat_idx)
// Sigmoid is monotone => top-k on logits == top-k on scores; descending sort
// on this key reproduces jax.lax.top_k order (ties: lower index first).
__global__ __launch_bounds__(NTHREADS) void postproc_kernel(
    const float* __restrict__ logits,
    const float4* __restrict__ boxes,
    float* __restrict__ out) {
  const int row = blockIdx.x;
  const int tid = threadIdx.x;

  __shared__ u64 s_keys[CAP];
  __shared__ int s_cnt;

  const float4* lp = (const float4*)logits + (size_t)row * NQ4;

  float T = T_INIT;
  float tlo = -1.0f, thi = 7.0f;  // bisection bounds for fallback
  int cnt = 0;

  auto filt = [&](float x, u32 idx) {
    if (x > T) {
      int pos = atomicAdd(&s_cnt, 1);
      if (pos < CAP)
        s_keys[pos] = ((u64)__float_as_uint(x) << 32) | (u64)(0xFFFFFFFFu - idx);
    }
  };

  for (int attempt = 0; attempt < 24; ++attempt) {
    __syncthreads();  // protect s_cnt reset vs. prior-iteration readers
    if (tid == 0) s_cnt = 0;
    __syncthreads();

    // scan: 4x unrolled (16 independent loads' addresses known up front)
    for (int i = tid; i < 16384; i += 4 * NTHREADS) {
      float4 v0 = lp[i];
      float4 v1 = lp[i + NTHREADS];
      float4 v2 = lp[i + 2 * NTHREADS];
      float4 v3 = lp[i + 3 * NTHREADS];
      filt(v0.x, 4 * i);                  filt(v0.y, 4 * i + 1);
      filt(v0.z, 4 * i + 2);              filt(v0.w, 4 * i + 3);
      int i1 = i + NTHREADS;
      filt(v1.x, 4 * i1);                 filt(v1.y, 4 * i1 + 1);
      filt(v1.z, 4 * i1 + 2);             filt(v1.w, 4 * i1 + 3);
      int i2 = i + 2 * NTHREADS;
      filt(v2.x, 4 * i2);                 filt(v2.y, 4 * i2 + 1);
      filt(v2.z, 4 * i2 + 2);             filt(v2.w, 4 * i2 + 3);
      int i3 = i + 3 * NTHREADS;
      filt(v3.x, 4 * i3);                 filt(v3.y, 4 * i3 + 1);
      filt(v3.z, 4 * i3 + 2);             filt(v3.w, 4 * i3 + 3);
    }
    for (int i = 16384 + tid; i < NQ4; i += NTHREADS) {
      float4 v = lp[i];
      filt(v.x, 4 * i);  filt(v.y, 4 * i + 1);
      filt(v.z, 4 * i + 2);  filt(v.w, 4 * i + 3);
    }

    __syncthreads();
    cnt = s_cnt;
    if (cnt >= TOPK && cnt <= CAP) break;
    // bisection: larger T -> fewer candidates
    if (cnt < TOPK) thi = T; else tlo = T;
    T = 0.5f * (tlo + thi);
  }
  if (cnt > CAP) cnt = CAP;

  // ---- register bitonic sort, descending, CAP=512 keys on threads 0..511.
  // Strides <=32: __shfl_xor (no barriers, 39 half-stages).
  // Strides 64/128/256: LDS exchange (6 half-stages, 12 barriers).
  u64 key = 0;
  if (tid < CAP && tid < cnt) key = s_keys[tid];

  for (int k = 2; k <= CAP; k <<= 1) {
    for (int j = k >> 1; j > 0; j >>= 1) {
      if (j >= 64) {
        __syncthreads();
        if (tid < CAP) s_keys[tid] = key;
        __syncthreads();
        if (tid < CAP) {
          u64 other = s_keys[tid ^ j];
          bool iLower = (tid & j) == 0;
          bool dirAsc = (tid & k) != 0;  // k=CAP => all-descending final
          bool keepMin = (dirAsc == iLower);
          key = keepMin ? (key < other ? key : other)
                        : (key > other ? key : other);
        }
      } else if (tid < CAP) {  // wave-uniform branch (tids >=512 whole waves)
        u64 other = shfl_xor_u64(key, j);
        bool iLower = (tid & j) == 0;
        bool dirAsc = (tid & k) != 0;
        bool keepMin = (dirAsc == iLower);
        key = keepMin ? (key < other ? key : other)
                      : (key > other ? key : other);
      }
    }
  }

  // ---- epilogue: thread tid holds the rank-tid key in register
  if (tid < TOPK) {
    float* labels_out = out;                  // [NB, TOPK]
    float* boxes_out = out + NB * TOPK;       // [NB, TOPK, 4]
    float* scores_out = out + NB * TOPK * 5;  // [NB, TOPK]

    float lab = 0.0f, score = 0.0f;
    float4 bo = make_float4(0.0f, 0.0f, 0.0f, 0.0f);
    if (tid < cnt) {
      u32 idx = 0xFFFFFFFFu - (u32)(key & 0xFFFFFFFFull);
      float x = __uint_as_float((u32)(key >> 32));
      int q = (int)(idx / NC);
      int c = (int)(idx - (u32)q * NC);
      lab = (float)c;
      score = (float)(1.0 / (1.0 + exp(-(double)x)));  // exact f32 sigmoid
      float4 bb = boxes[(size_t)row * NQ + q];
      float hw = 0.5f * bb.z, hh = 0.5f * bb.w;
      bo.x = bb.x - hw;
      bo.y = bb.y - hh;
      bo.z = bb.x + hw;
      bo.w = bb.y + hh;
    }
    labels_out[row * TOPK + tid] = lab;
    scores_out[row * TOPK + tid] = score;
    ((float4*)boxes_out)[row * TOPK + tid] = bo;
  }
}

extern "C" void kernel_launch(void* const* d_in, const int* in_sizes, int n_in,
                              void* d_out, int out_size, void* d_ws, size_t ws_size,
                              hipStream_t stream) {
  const float* logits = (const float*)d_in[0];
  const float4* boxes = (const float4*)d_in[1];
  float* out = (float*)d_out;
  postproc_kernel<<<NB, NTHREADS, 0, stream>>>(logits, boxes, out);
}